// Round 8
// baseline (292.163 us; speedup 1.0000x reference)
//
#include <hip/hip_runtime.h>
#include <stdint.h>

typedef unsigned short u16;
typedef short short8 __attribute__((ext_vector_type(8)));
typedef float f32x4 __attribute__((ext_vector_type(4)));

// ---------- helpers ----------
__device__ __forceinline__ u16 f2bf_fast(float f) {
  union { float f; uint32_t u; } x;
  x.f = f;
  return (u16)((x.u + 0x8000u) >> 16);
}

__device__ __forceinline__ uint32_t pack2bf(float lo, float hi) {
  union { float f; uint32_t u; } a, b;
  a.f = lo; b.f = hi;
  return __builtin_amdgcn_perm(b.u + 0x8000u, a.u + 0x8000u, 0x07060302u);
}

__device__ __forceinline__ float bf2f(uint32_t u) {
  union { uint32_t u; float f; } x;
  x.u = u << 16;
  return x.f;
}

__device__ __forceinline__ f32x4 mfma16(short8 a, short8 b, f32x4 c) {
  return __builtin_amdgcn_mfma_f32_16x16x32_bf16(a, b, c, 0, 0, 0);
}

// P32 packed fragment load: granule = ((tile*32+kc)*64+lane)*8 u16
__device__ __forceinline__ short8 ldfrag(const u16* base, int tile, int kc,
                                         int lane) {
  return *(const short8*)(base + ((((tile << 5) + kc) << 6) + lane) * 8);
}

#define QSCALE 0.18033688011112042f

// ---------- pack fp32 -> bf16 P32 fragment layout ----------
__global__ void pack_all(const float* __restrict__ x, const float* __restrict__ wq,
                         const float* __restrict__ wk, const float* __restrict__ wv,
                         const float* __restrict__ wo, u16* __restrict__ xp,
                         u16* __restrict__ wp) {
  const int gi = blockIdx.x * 256 + threadIdx.x;
  const int lane = gi & 63;
  const int kc = (gi >> 6) & 31;
  const int rt = gi >> 11;
  const int col = kc * 32 + (lane >> 4) * 8;
  const float* src;
  int row;
  if (rt < 256) {
    src = x;
    row = rt * 16 + (lane & 15);
  } else {
    const int wti = rt - 256;
    const int widx = wti >> 6;
    src = (widx == 0) ? wq : (widx == 1) ? wk : (widx == 2) ? wv : wo;
    row = (wti & 63) * 16 + (lane & 15);
  }
  const float4* p = (const float4*)(src + (size_t)row * 1024 + col);
  const float4 v0 = p[0], v1 = p[1];
  uint4 o;
  o.x = pack2bf(v0.x, v0.y);
  o.y = pack2bf(v0.z, v0.w);
  o.z = pack2bf(v1.x, v1.y);
  o.w = pack2bf(v1.z, v1.w);
  u16* dst = (rt < 256) ? xp : wp;
  const int og = (rt < 256) ? gi : gi - 524288;
  ((uint4*)dst)[og] = o;
}

// ---------- LDS-free projection GEMM, XCD-partitioned ----------
// Writes Q/K/V in per-bh MFMA-fragment-packed layouts (K with sigma baked):
//  qp[bh][granule=(s>>4)*2+(d>>5)][lane=((d>>3)&3)*16+(s&15)][j=d&7]
//  kp: same but lane low-4 = sigma(s&15)  (sigma swaps bits 2,3)
//  vp[bh][granule=(dd>>4)*64+(s>>5)][lane=((s>>3)&3)*16+(dd&15)][j=s&7]
__global__ __launch_bounds__(256, 3) void proj_qkv(
    const u16* __restrict__ xp, const u16* __restrict__ wp,
    const float* __restrict__ bq, const float* __restrict__ bk,
    const float* __restrict__ bv, u16* __restrict__ qp, u16* __restrict__ kp,
    u16* __restrict__ vp) {
  const int wv2 = threadIdx.x >> 6;
  const int lane = threadIdx.x & 63;
  const int quad = lane >> 4, l15 = lane & 15;
  const int xcd = blockIdx.x & 7;
  const int bidx = blockIdx.x >> 3;  // 0..95
  const int xq = xcd >> 1, xh = xcd & 1;
  const bool isQK = bidx < 64;
  int at0, bt0, bm, bn;
  const u16 *Ap, *Bp;
  if (isQK) {
    const int q = bidx;
    bn = xh * 16 + (q & 15);
    bm = xq * 16 + (q >> 4) * 4 + wv2;
    Ap = xp; at0 = bm * 4;
    Bp = wp; bt0 = bn * 4;
  } else {
    const int v = bidx - 64;
    bn = xq * 16 + (v & 15);
    bm = xh * 8 + (v >> 4) * 4 + wv2;
    Ap = wp; at0 = 128 + bm * 4;
    Bp = xp; bt0 = bn * 4;
  }

  f32x4 acc[4][4] = {};
  short8 af[2][4], bf[2][4];
#pragma unroll
  for (int mt = 0; mt < 4; ++mt) af[0][mt] = ldfrag(Ap, at0 + mt, 0, lane);
#pragma unroll
  for (int nt = 0; nt < 4; ++nt) bf[0][nt] = ldfrag(Bp, bt0 + nt, 0, lane);

#pragma unroll 4
  for (int kc = 0; kc < 32; ++kc) {
    const int cur = kc & 1, nxt = cur ^ 1;
    if (kc < 31) {
#pragma unroll
      for (int mt = 0; mt < 4; ++mt)
        af[nxt][mt] = ldfrag(Ap, at0 + mt, kc + 1, lane);
#pragma unroll
      for (int nt = 0; nt < 4; ++nt)
        bf[nxt][nt] = ldfrag(Bp, bt0 + nt, kc + 1, lane);
    }
#pragma unroll
    for (int mt = 0; mt < 4; ++mt)
#pragma unroll
      for (int nt = 0; nt < 4; ++nt)
        acc[mt][nt] = mfma16(af[cur][mt], bf[cur][nt], acc[mt][nt]);
  }

#pragma unroll
  for (int nt = 0; nt < 4; ++nt) {
    const int n = bn * 64 + nt * 16 + l15;
#pragma unroll
    for (int mt = 0; mt < 4; ++mt)
#pragma unroll
      for (int r = 0; r < 4; ++r) {
        const int m = bm * 64 + mt * 16 + quad * 4 + r;
        const float a = acc[mt][nt][r];
        if (isQK) {
          const bool isQ = (bn < 16);
          const int nn = isQ ? n : n - 1024;
          const int hh = nn >> 6, d = nn & 63;
          const int b = m >> 11, s2 = m & 2047;
          const int bh = b * 16 + hh;
          const float v = isQ ? (a + bq[nn]) * QSCALE : a + bk[nn];
          const int s4 = s2 & 15;
          const int lp_ = isQ ? s4 : ((s4 & 3) | ((s4 >> 1) & 4) | ((s4 << 1) & 8));
          u16* dst = isQ ? qp : kp;
          dst[((size_t)bh * 256 + (s2 >> 4) * 2 + (d >> 5)) * 512 +
              ((((d >> 3) & 3) * 16 + lp_) * 8) + (d & 7)] = f2bf_fast(v);
        } else {
          const int hh = m >> 6, dd = m & 63;
          const int b = n >> 11, s2 = n & 2047;
          const int bh = b * 16 + hh;
          const float v = a + bv[m];
          vp[((size_t)bh * 256 + (dd >> 4) * 64 + (s2 >> 5)) * 512 +
             ((((s2 >> 3) & 3) * 16 + (dd & 15)) * 8) + (s2 & 7)] = f2bf_fast(v);
        }
      }
  }
}

// ---------- flash attention: barrier-free, LDS-free, fragment-packed ----------
// grid (16 qt, 64=bh*2+ks); 4 waves/block, each wave independently owns 32
// q-rows = (qt*4+w)*32..+31 and loops over 16 x 64-key tiles of its ks half.
// All operands are b128 global loads from packed layouts (L1/L2-served);
// compiler pipelines with vmcnt(N) -- no __syncthreads anywhere.
// S^T = K @ Q^T (K rows sigma-permuted in layout); P^T assembled in-register
// (R7-verified shfl path); O^T += V^T @ P^T at K=32.
__global__ __launch_bounds__(256) void attn_kernel(
    const u16* __restrict__ qp, const u16* __restrict__ kp,
    const u16* __restrict__ vp, u16* __restrict__ op0, u16* __restrict__ op1,
    float* __restrict__ lp) {
  const int tid = threadIdx.x, lane = tid & 63, w = tid >> 6;
  const int quad = lane >> 4, l15 = lane & 15;
  const int qt = blockIdx.x;
  const int bh = blockIdx.y >> 1;
  const int ks = blockIdx.y & 1;

  const u16* qb = qp + (size_t)bh * 131072;
  const u16* kb = kp + (size_t)bh * 131072;
  const u16* vb = vp + (size_t)bh * 131072;

  // Q fragments (loop-invariant): rt = (qt*4+w)*2+mt
  short8 aq[2][2];
#pragma unroll
  for (int mt = 0; mt < 2; ++mt)
#pragma unroll
    for (int kc = 0; kc < 2; ++kc)
      aq[mt][kc] = *(const short8*)(qb +
          ((((size_t)((qt * 4 + w) * 2 + mt) * 2 + kc) << 6) + lane) * 8);

  f32x4 ot[4][2] = {};
  float lsum[2] = {};

#pragma unroll 2
  for (int kt = 0; kt < 16; ++kt) {
    // K fragments: key-tiles ks*64 + kt*4 + ntk, kc 0..1
    short8 kf[4][2];
#pragma unroll
    for (int ntk = 0; ntk < 4; ++ntk)
#pragma unroll
      for (int kc = 0; kc < 2; ++kc)
        kf[ntk][kc] = *(const short8*)(kb +
            ((((size_t)(ks * 64 + kt * 4 + ntk) * 2 + kc) << 6) + lane) * 8);
    // V fragments: 32-key groups ks*32 + kt*2 + g, d-tiles 0..3
    short8 vf[4][2];
#pragma unroll
    for (int ntd = 0; ntd < 4; ++ntd)
#pragma unroll
      for (int g = 0; g < 2; ++g)
        vf[ntd][g] = *(const short8*)(vb +
            (((size_t)(ntd * 64 + ks * 32 + kt * 2 + g) << 6) + lane) * 8);

    // S^T = K @ Q^T; C entry (quad,r) of tile ntk = key ntk*16+sigma(quad*4+r)
    f32x4 st[2][4] = {};
#pragma unroll
    for (int kc = 0; kc < 2; ++kc)
#pragma unroll
      for (int ntk = 0; ntk < 4; ++ntk) {
        st[0][ntk] = mfma16(kf[ntk][kc], aq[0][kc], st[0][ntk]);
        st[1][ntk] = mfma16(kf[ntk][kc], aq[1][kc], st[1][ntk]);
      }

    // exp2 + pack: tile ntk regs hold an aligned 4-key run per quad
    uint2 pp[2][4];
#pragma unroll
    for (int mt = 0; mt < 2; ++mt)
#pragma unroll
      for (int ntk = 0; ntk < 4; ++ntk) {
        const float e0 = __builtin_amdgcn_exp2f(st[mt][ntk][0]);
        const float e1 = __builtin_amdgcn_exp2f(st[mt][ntk][1]);
        const float e2 = __builtin_amdgcn_exp2f(st[mt][ntk][2]);
        const float e3 = __builtin_amdgcn_exp2f(st[mt][ntk][3]);
        lsum[mt] += (e0 + e1) + (e2 + e3);
        pp[mt][ntk].x = pack2bf(e0, e1);
        pp[mt][ntk].y = pack2bf(e2, e3);
      }

    // assemble K=32 B-operands (R7-verified): group g uses tiles 2g,2g+1
    short8 pf[2][2];
#pragma unroll
    for (int mt = 0; mt < 2; ++mt)
#pragma unroll
      for (int g = 0; g < 2; ++g) {
        const uint2 o0 = pp[mt][2 * g], o1 = pp[mt][2 * g + 1];
        const uint32_t x0l = __shfl_xor(o0.x, 32), x0h = __shfl_xor(o0.y, 32);
        const uint32_t x1l = __shfl_xor(o1.x, 32), x1h = __shfl_xor(o1.y, 32);
        union { uint32_t u[4]; short8 s; } f;
        if (quad < 2) {
          f.u[0] = o0.x; f.u[1] = o0.y; f.u[2] = x0l; f.u[3] = x0h;
        } else {
          f.u[0] = x1l; f.u[1] = x1h; f.u[2] = o1.x; f.u[3] = o1.y;
        }
        pf[mt][g] = f.s;
      }

    // O^T += V^T @ P^T
#pragma unroll
    for (int g = 0; g < 2; ++g)
#pragma unroll
      for (int ntd = 0; ntd < 4; ++ntd) {
        ot[ntd][0] = mfma16(vf[ntd][g], pf[0][g], ot[ntd][0]);
        ot[ntd][1] = mfma16(vf[ntd][g], pf[1][g], ot[ntd][1]);
      }
  }

  // epilogue: packed o-partials + l-partials
  const int b = bh >> 4, h = bh & 15;
  u16* op = ks ? op1 : op0;
#pragma unroll
  for (int mt = 0; mt < 2; ++mt) {
    float l = lsum[mt];
    l += __shfl_xor(l, 16);
    l += __shfl_xor(l, 32);
    const int srow = qt * 128 + w * 32 + mt * 16 + l15;
    if (quad == 0) lp[((size_t)(ks * 32 + bh)) * 2048 + srow] = l;
    const int rt = b * 128 + qt * 8 + w * 2 + mt;
#pragma unroll
    for (int ntd = 0; ntd < 4; ++ntd) {
      const int kc = h * 2 + (ntd >> 1);
      const int lnq = ((ntd & 1) * 2 + (quad >> 1)) & 3;
      const int j0 = (quad & 1) * 4;
      uint2 ov;
      ov.x = pack2bf(ot[ntd][mt][0], ot[ntd][mt][1]);
      ov.y = pack2bf(ot[ntd][mt][2], ot[ntd][mt][3]);
      *(uint2*)(op + ((size_t)((rt * 32 + kc) * 64 + lnq * 16 + l15)) * 8 + j0) = ov;
    }
  }
}

// ---------- combine (packed granule-wise): awp = (o0+o1)/(l0+l1) ----------
__global__ void attn_combine(const u16* __restrict__ op0,
                             const u16* __restrict__ op1,
                             const float* __restrict__ lp,
                             u16* __restrict__ awp) {
  const int g = blockIdx.x * 256 + threadIdx.x;
  const int ln = g & 63;
  const int kc = (g >> 6) & 31;
  const int rt = g >> 11;
  const int row = rt * 16 + (ln & 15);
  const int b = row >> 11, s = row & 2047;
  const int h = kc >> 1;
  const int lidx = (b * 16 + h) * 2048 + s;
  const float inv = __builtin_amdgcn_rcpf(lp[lidx] + lp[lidx + 65536]);
  const uint4 a0 = ((const uint4*)op0)[g];
  const uint4 a1 = ((const uint4*)op1)[g];
  uint4 o;
  o.x = pack2bf((bf2f(a0.x) + bf2f(a1.x)) * inv,
                (bf2f(a0.x >> 16) + bf2f(a1.x >> 16)) * inv);
  o.y = pack2bf((bf2f(a0.y) + bf2f(a1.y)) * inv,
                (bf2f(a0.y >> 16) + bf2f(a1.y >> 16)) * inv);
  o.z = pack2bf((bf2f(a0.z) + bf2f(a1.z)) * inv,
                (bf2f(a0.z >> 16) + bf2f(a1.z >> 16)) * inv);
  o.w = pack2bf((bf2f(a0.w) + bf2f(a1.w)) * inv,
                (bf2f(a0.w >> 16) + bf2f(a1.w >> 16)) * inv);
  ((uint4*)awp)[g] = o;
}

// ---------- LDS-free out projection, XCD-partitioned ----------
__global__ __launch_bounds__(256, 3) void out_proj(const u16* __restrict__ awp,
                                                   const u16* __restrict__ wp,
                                                   const float* __restrict__ bo,
                                                   float* __restrict__ out) {
  const int wv2 = threadIdx.x >> 6;
  const int lane = threadIdx.x & 63;
  const int quad = lane >> 4, l15 = lane & 15;
  const int xcd = blockIdx.x & 7;
  const int bidx = blockIdx.x >> 3;  // 0..63
  const int xq = xcd >> 1, xh = xcd & 1;
  const int bnn = xh * 16 + (bidx & 15);
  const int bm = xq * 16 + (bidx >> 4) * 4 + wv2;
  const int at0 = bm * 4, bt0 = 192 + bnn * 2;

  f32x4 acc[4][2] = {};
  short8 af[2][4], bf[2][2];
#pragma unroll
  for (int mt = 0; mt < 4; ++mt) af[0][mt] = ldfrag(awp, at0 + mt, 0, lane);
#pragma unroll
  for (int nt = 0; nt < 2; ++nt) bf[0][nt] = ldfrag(wp, bt0 + nt, 0, lane);

#pragma unroll 4
  for (int kc = 0; kc < 32; ++kc) {
    const int cur = kc & 1, nxt = cur ^ 1;
    if (kc < 31) {
#pragma unroll
      for (int mt = 0; mt < 4; ++mt)
        af[nxt][mt] = ldfrag(awp, at0 + mt, kc + 1, lane);
#pragma unroll
      for (int nt = 0; nt < 2; ++nt)
        bf[nxt][nt] = ldfrag(wp, bt0 + nt, kc + 1, lane);
    }
#pragma unroll
    for (int mt = 0; mt < 4; ++mt)
#pragma unroll
      for (int nt = 0; nt < 2; ++nt)
        acc[mt][nt] = mfma16(af[cur][mt], bf[cur][nt], acc[mt][nt]);
  }

#pragma unroll
  for (int nt = 0; nt < 2; ++nt) {
    const int n = bnn * 32 + nt * 16 + l15;
    const float bb = bo[n];
#pragma unroll
    for (int mt = 0; mt < 4; ++mt)
#pragma unroll
      for (int r = 0; r < 4; ++r) {
        const int m = bm * 64 + mt * 16 + quad * 4 + r;
        out[(size_t)m * 1024 + n] = acc[mt][nt][r] + bb;
      }
  }
}

// ---------- launch ----------
extern "C" void kernel_launch(void* const* d_in, const int* in_sizes, int n_in,
                              void* d_out, int out_size, void* d_ws, size_t ws_size,
                              hipStream_t stream) {
  const float* x  = (const float*)d_in[0];
  const float* Wq = (const float*)d_in[1];
  const float* bq = (const float*)d_in[2];
  const float* Wk = (const float*)d_in[3];
  const float* bk = (const float*)d_in[4];
  const float* Wv = (const float*)d_in[5];
  const float* bv = (const float*)d_in[6];
  const float* Wo = (const float*)d_in[7];
  const float* bo = (const float*)d_in[8];

  const size_t M4 = (size_t)4 * 1024 * 1024;
  u16* xp  = (u16*)d_ws;
  u16* wp  = xp + M4;
  u16* qp  = wp + M4;
  u16* kp  = qp + M4;
  u16* vp  = kp + M4;
  u16* op1 = vp + M4;
  u16* awp = op1 + M4;
  float* lp = (float*)(awp + M4);
  u16* op0 = xp;

  pack_all<<<4096, 256, 0, stream>>>(x, Wq, Wk, Wv, Wo, xp, wp);

  proj_qkv<<<768, 256, 0, stream>>>(xp, wp, bq, bk, bv, qp, kp, vp);

  attn_kernel<<<dim3(16, 64), 256, 0, stream>>>(qp, kp, vp, op0, op1, lp);

  attn_combine<<<2048, 256, 0, stream>>>(op0, op1, lp, awp);

  out_proj<<<512, 256, 0, stream>>>(awp, wp, bo, (float*)d_out);
}